// Round 2
// baseline (256.743 us; speedup 1.0000x reference)
//
#include <hip/hip_runtime.h>

#define H1 64
#define GAMMA 0.1f

// One wave (64 lanes) per row m. Lane h owns channel h's scalar SIR ODE
// (constant beta), integrates with RK4 in registers, and cooperates in the
// per-timestep head via staged cross-lane butterfly reductions.
__global__ __launch_bounds__(256) void sir_ode_kernel(
    const float* __restrict__ x,
    const float* __restrict__ t,
    const float* __restrict__ W_s1,
    const float* __restrict__ b_s1,
    const float* __restrict__ W3,
    const float* __restrict__ b3,
    const float* __restrict__ Ws2,
    float* __restrict__ out,
    int M, int T)
{
    const int gtid = blockIdx.x * blockDim.x + threadIdx.x;
    const int m = gtid >> 6;
    const int lane = threadIdx.x & 63;
    if (m >= M) return;

    const int C = H1 + 3;
    const int h = lane;
    const int g = lane >> 4;   // k-group: this 16-lane group owns W3 row k=g

    // per-lane constants
    const float w30 = W3[0 * H1 + h];
    const float w31 = W3[1 * H1 + h];
    const float w32 = W3[2 * H1 + h];
    const float w33 = W3[3 * H1 + h];
    const float b3g  = b3[g];
    const float ws2g = Ws2[g];

    const float S0  = x[(size_t)m * C + 0];
    const float I0  = x[(size_t)m * C + 1];
    const float bgv = x[(size_t)m * C + 3 + h];
    const float w1  = W_s1[h];
    const float bb  = b_s1[h];

    float S = fmaxf(fmaf(S0, w1, bb), 0.0f);
    float I = fmaxf(fmaf(I0, w1, bb), 0.0f);
    float R = 0.0f;
    const float beta = 0.5f / (1.0f + __expf(-bgv));

    const size_t TM = (size_t)T * (size_t)M;
    float t_cur = t[0];

    for (int ti = 0; ti < T; ++ti) {
        // issue the (uniform) next-time load early so latency hides under the head
        float dt = 0.0f;
        if (ti + 1 < T) dt = t[ti + 1] - t_cur;

        // ---- head: 12 partial products (3 states x 4 W3 rows), per lane h
        float p0 = S * w30, p1 = S * w31, p2  = S * w32, p3  = S * w33;
        float p4 = I * w30, p5 = I * w31, p6  = I * w32, p7  = I * w33;
        float p8 = R * w30, p9 = R * w31, p10 = R * w32, p11 = R * w33;

        // stage A: fold the four 16-lane groups together (xor 16, 32).
        // After this, lane l holds the partial sum over h in {l&15, +16, +32, +48}.
#define RED2(v) v += __shfl_xor(v, 16); v += __shfl_xor(v, 32);
        RED2(p0) RED2(p1) RED2(p2)  RED2(p3)
        RED2(p4) RED2(p5) RED2(p6)  RED2(p7)
        RED2(p8) RED2(p9) RED2(p10) RED2(p11)
#undef RED2

        // each 16-lane group specializes to k = g: pick its 3 state-partials
        float q0 = (g < 2) ? ((g == 0) ? p0 : p1) : ((g == 2) ? p2  : p3);
        float q1 = (g < 2) ? ((g == 0) ? p4 : p5) : ((g == 2) ? p6  : p7);
        float q2 = (g < 2) ? ((g == 0) ? p8 : p9) : ((g == 2) ? p10 : p11);

        // stage B: reduce within the 16-lane group (xor 1,2,4,8) -> full 64-dot
#define RED4(v) v += __shfl_xor(v, 1); v += __shfl_xor(v, 2); \
                v += __shfl_xor(v, 4); v += __shfl_xor(v, 8);
        RED4(q0) RED4(q1) RED4(q2)
#undef RED4

        // per-k nonlinearity: relu(dot + b3[k]) * Ws2[k]
        float h0 = fmaxf(q0 + b3g, 0.0f) * ws2g;
        float h1 = fmaxf(q1 + b3g, 0.0f) * ws2g;
        float h2 = fmaxf(q2 + b3g, 0.0f) * ws2g;

        // stage C: sum the 4 k-groups (xor 16, 32) -> logits on every lane.
        // bs2 is added to all 3 logits equally -> cancels in softmax.
        h0 += __shfl_xor(h0, 16); h0 += __shfl_xor(h0, 32);
        h1 += __shfl_xor(h1, 16); h1 += __shfl_xor(h1, 32);
        h2 += __shfl_xor(h2, 16); h2 += __shfl_xor(h2, 32);

        // softmax over the 3 states
        float mx = fmaxf(fmaxf(h0, h1), h2);
        float e0 = __expf(h0 - mx);
        float e1 = __expf(h1 - mx);
        float e2 = __expf(h2 - mx);
        float rs = 1.0f / (e0 + e1 + e2);

        if (lane < 3) {
            float v = (lane == 0) ? e0 * rs : ((lane == 1) ? e1 * rs : e2 * rs);
            out[(size_t)lane * TM + (size_t)ti * M + m] = v;
        }

        // ---- RK4 advance (dS = -beta*S*I, dI = beta*S*I - g*I, dR = g*I)
        if (ti + 1 < T) {
            t_cur += dt;
            const float hdt = 0.5f * dt;

            float inf1 = beta * S * I;
            float k1s = -inf1;
            float k1i = fmaf(-GAMMA, I, inf1);
            float S2 = fmaf(hdt, k1s, S);
            float I2 = fmaf(hdt, k1i, I);

            float inf2 = beta * S2 * I2;
            float k2s = -inf2;
            float k2i = fmaf(-GAMMA, I2, inf2);
            float S3 = fmaf(hdt, k2s, S);
            float I3 = fmaf(hdt, k2i, I);

            float inf3 = beta * S3 * I3;
            float k3s = -inf3;
            float k3i = fmaf(-GAMMA, I3, inf3);
            float S4 = fmaf(dt, k3s, S);
            float I4 = fmaf(dt, k3i, I);

            float inf4 = beta * S4 * I4;
            float k4s = -inf4;
            float k4i = fmaf(-GAMMA, I4, inf4);

            const float w = dt * (1.0f / 6.0f);
            // R increment uses the OLD I (k1R = GAMMA * I_old)
            float Rinc = w * GAMMA * (I + 2.0f * (I2 + I3) + I4);
            S += w * (k1s + 2.0f * (k2s + k3s) + k4s);
            I += w * (k1i + 2.0f * (k2i + k3i) + k4i);
            R += Rinc;
        }
    }
}

extern "C" void kernel_launch(void* const* d_in, const int* in_sizes, int n_in,
                              void* d_out, int out_size, void* d_ws, size_t ws_size,
                              hipStream_t stream) {
    const float* x    = (const float*)d_in[0];
    const float* t    = (const float*)d_in[1];
    const float* W_s1 = (const float*)d_in[2];
    const float* b_s1 = (const float*)d_in[3];
    const float* W3   = (const float*)d_in[4];
    const float* b3   = (const float*)d_in[5];
    const float* Ws2  = (const float*)d_in[6];
    // d_in[7] = bs2: cancels in the softmax, unused.
    float* out = (float*)d_out;

    const int M = in_sizes[0] / (H1 + 3);   // 4000
    const int T = in_sizes[1];              // 100

    const int threads = 256;                 // 4 waves/block
    const int blocks = (M * 64 + threads - 1) / threads;
    sir_ode_kernel<<<blocks, threads, 0, stream>>>(x, t, W_s1, b_s1, W3, b3, Ws2,
                                                   out, M, T);
}

// Round 3
// 253.861 us; speedup vs baseline: 1.0114x; 1.0114x over previous
//
#include <hip/hip_runtime.h>

#define H1 64
#define GAMMA 0.1f
#define U 4

// ---- DS-free cross-lane reductions (all VALU pipe) ----

// DPP xor-pattern folds within a 16-lane row. Masks {1,2,7,15} span F_2^4,
// so applying all four leaves every lane holding the full 16-lane row sum.
#define DPP_QUAD_XOR1  0xB1   // quad_perm [1,0,3,2]  -> partner lane^1
#define DPP_QUAD_XOR2  0x4E   // quad_perm [2,3,0,1]  -> partner lane^2
#define DPP_HALF_MIRR  0x141  // row_half_mirror      -> partner lane^7
#define DPP_ROW_MIRR   0x140  // row_mirror           -> partner lane^15

#define DPP_FOLD(v, ctrl)                                                     \
  { int _p = __builtin_amdgcn_update_dpp(0, __float_as_int(v), (ctrl), 0xF,   \
                                         0xF, true);                          \
    (v) += __int_as_float(_p); }

static __device__ __forceinline__ float red_row16(float v) {
    DPP_FOLD(v, DPP_QUAD_XOR1);
    DPP_FOLD(v, DPP_QUAD_XOR2);
    DPP_FOLD(v, DPP_HALF_MIRR);
    DPP_FOLD(v, DPP_ROW_MIRR);
    return v;
}

// fold16: v += v[lane^16]; fold32: v += v[lane^32]. gfx950 permlane*_swap
// returns both halves of the swap: with A=B=v, r.x+r.y is the butterfly sum
// on every lane. Fallback: __shfl_xor (DS pipe) — correct either way.
static __device__ __forceinline__ float fold16(float v) {
#if __has_builtin(__builtin_amdgcn_permlane16_swap)
    typedef unsigned u32x2 __attribute__((ext_vector_type(2)));
    u32x2 r = __builtin_amdgcn_permlane16_swap(__float_as_uint(v),
                                               __float_as_uint(v), false, false);
    return __uint_as_float(r.x) + __uint_as_float(r.y);
#else
    return v + __shfl_xor(v, 16);
#endif
}
static __device__ __forceinline__ float fold32(float v) {
#if __has_builtin(__builtin_amdgcn_permlane32_swap)
    typedef unsigned u32x2 __attribute__((ext_vector_type(2)));
    u32x2 r = __builtin_amdgcn_permlane32_swap(__float_as_uint(v),
                                               __float_as_uint(v), false, false);
    return __uint_as_float(r.x) + __uint_as_float(r.y);
#else
    return v + __shfl_xor(v, 32);
#endif
}

// One wave per row m; lane h owns channel h. R is never integrated:
// S+I+R is conserved per channel, so dot(R,w3k) = cst_k - dotS_k - dotI_k.
__global__ __launch_bounds__(256) void sir_ode_kernel(
    const float* __restrict__ x,
    const float* __restrict__ t,
    const float* __restrict__ W_s1,
    const float* __restrict__ b_s1,
    const float* __restrict__ W3,
    const float* __restrict__ b3,
    const float* __restrict__ Ws2,
    float* __restrict__ out,
    int M, int T)
{
    const int gtid = blockIdx.x * blockDim.x + threadIdx.x;
    const int m = gtid >> 6;
    const int lane = threadIdx.x & 63;
    if (m >= M) return;

    const int C = H1 + 3;
    const int g = (lane >> 4) & 3;   // this 16-lane row owns W3 row k=g

    const float w30 = W3[0 * H1 + lane];
    const float w31 = W3[1 * H1 + lane];
    const float w32 = W3[2 * H1 + lane];
    const float w33 = W3[3 * H1 + lane];
    const float b3g  = b3[g];
    const float ws2g = Ws2[g];

    const float S0  = x[(size_t)m * C + 0];
    const float I0  = x[(size_t)m * C + 1];
    const float bgv = x[(size_t)m * C + 3 + lane];
    const float w1  = W_s1[lane];
    const float bb  = b_s1[lane];

    float S = fmaxf(fmaf(S0, w1, bb), 0.0f);
    float I = fmaxf(fmaf(I0, w1, bb), 0.0f);
    const float beta = 0.5f / (1.0f + __expf(-bgv));

    // conserved-total constant for this lane's k-group:
    // cst_g = sum_h W3[g,h] * (S0c[h] + I0c[h])
    float cst;
    {
        const float tot = S + I;
        float c0 = tot * w30, c1 = tot * w31, c2 = tot * w32, c3 = tot * w33;
        c0 = fold32(fold16(c0)); c1 = fold32(fold16(c1));
        c2 = fold32(fold16(c2)); c3 = fold32(fold16(c3));
        float cA = (g & 1) ? c1 : c0;
        float cB = (g & 1) ? c3 : c2;
        cst = red_row16((g & 2) ? cB : cA);
    }

    const size_t TM = (size_t)T * (size_t)M;
    float t_cur = t[0];

    // dt for step->step+1 (0 beyond the end); maintains t_cur.
    auto next_dt = [&](int step) -> float {
        int idx = step + 1;
        if (idx >= T) return 0.0f;         // uniform branch
        float tn = t[idx];
        float d = tn - t_cur;
        t_cur = tn;
        return d;
    };

    // one RK4 advance of (S,I); dt==0 is an exact no-op.
    auto adv = [&](float dt) {
        const float hdt = 0.5f * dt;
        float inf1 = beta * S * I;
        float I2 = fmaf(hdt, fmaf(-GAMMA, I, inf1), I);
        float S2 = fmaf(-hdt, inf1, S);
        float inf2 = beta * S2 * I2;
        float S3 = fmaf(-hdt, inf2, S);
        float I3 = fmaf(hdt, fmaf(-GAMMA, I2, inf2), I);
        float inf3 = beta * S3 * I3;
        float S4 = fmaf(-dt, inf3, S);
        float I4 = fmaf(dt, fmaf(-GAMMA, I3, inf3), I);
        float inf4 = beta * S4 * I4;
        float sumInf = fmaf(2.0f, inf2 + inf3, inf1) + inf4;
        float A      = fmaf(2.0f, I2 + I3, I) + I4;
        float w = dt * (1.0f / 6.0f);
        S = fmaf(-w, sumInf, S);
        I = fmaf(w, fmaf(-GAMMA, A, sumInf), I);
    };

    // prologue: snapshots for group 0; S,I end at y(U)
    float Ss[U], Is[U];
#pragma unroll
    for (int u = 0; u < U; ++u) { Ss[u] = S; Is[u] = I; adv(next_dt(u)); }

    for (int t0 = 0; t0 < T; t0 += U) {
        // 1) per-lane partials for the current 4 snapshots
        float pS[U][4], pI[U][4];
#pragma unroll
        for (int u = 0; u < U; ++u) {
            pS[u][0] = Ss[u] * w30; pS[u][1] = Ss[u] * w31;
            pS[u][2] = Ss[u] * w32; pS[u][3] = Ss[u] * w33;
            pI[u][0] = Is[u] * w30; pI[u][1] = Is[u] * w31;
            pI[u][2] = Is[u] * w32; pI[u][3] = Is[u] * w33;
        }
        // stage A: fold residue classes across the four 16-lane rows
#pragma unroll
        for (int u = 0; u < U; ++u) {
#pragma unroll
            for (int k = 0; k < 4; ++k) {
                pS[u][k] = fold32(fold16(pS[u][k]));
                pI[u][k] = fold32(fold16(pI[u][k]));
            }
        }

        // 2) advance next group's snapshots — independent VALU work the
        //    scheduler can sink into fold-latency shadows
        float Sn[U], In[U];
#pragma unroll
        for (int u = 0; u < U; ++u) {
            Sn[u] = S; In[u] = I;
            adv(next_dt(t0 + U + u));
        }

        // 3) specialize per 16-lane row, finish dots, head, softmax, store
#pragma unroll
        for (int u = 0; u < U; ++u) {
            float qsA = (g & 1) ? pS[u][1] : pS[u][0];
            float qsB = (g & 1) ? pS[u][3] : pS[u][2];
            float qs  = red_row16((g & 2) ? qsB : qsA);
            float qiA = (g & 1) ? pI[u][1] : pI[u][0];
            float qiB = (g & 1) ? pI[u][3] : pI[u][2];
            float qi  = red_row16((g & 2) ? qiB : qiA);
            float qr  = cst - qs - qi;

            float h0 = fmaxf(qs + b3g, 0.0f) * ws2g;
            float h1 = fmaxf(qi + b3g, 0.0f) * ws2g;
            float h2 = fmaxf(qr + b3g, 0.0f) * ws2g;
            // stage C: sum the 4 k-groups (bs2 cancels in softmax)
            h0 = fold32(fold16(h0));
            h1 = fold32(fold16(h1));
            h2 = fold32(fold16(h2));

            float mx = fmaxf(fmaxf(h0, h1), h2);
            float e0 = __expf(h0 - mx);
            float e1 = __expf(h1 - mx);
            float e2 = __expf(h2 - mx);
            float rs = 1.0f / (e0 + e1 + e2);

            int step = t0 + u;
            if (step < T && lane < 3) {
                float v = (lane == 0) ? e0 * rs : ((lane == 1) ? e1 * rs : e2 * rs);
                out[(size_t)lane * TM + (size_t)step * M + m] = v;
            }
        }

        // 4) rotate snapshots
#pragma unroll
        for (int u = 0; u < U; ++u) { Ss[u] = Sn[u]; Is[u] = In[u]; }
    }
}

extern "C" void kernel_launch(void* const* d_in, const int* in_sizes, int n_in,
                              void* d_out, int out_size, void* d_ws, size_t ws_size,
                              hipStream_t stream) {
    const float* x    = (const float*)d_in[0];
    const float* t    = (const float*)d_in[1];
    const float* W_s1 = (const float*)d_in[2];
    const float* b_s1 = (const float*)d_in[3];
    const float* W3   = (const float*)d_in[4];
    const float* b3   = (const float*)d_in[5];
    const float* Ws2  = (const float*)d_in[6];
    // d_in[7] = bs2: cancels in the softmax, unused.
    float* out = (float*)d_out;

    const int M = in_sizes[0] / (H1 + 3);   // 4000
    const int T = in_sizes[1];              // 100

    const int threads = 256;                 // 4 waves/block
    const int blocks = (M * 64 + threads - 1) / threads;
    sir_ode_kernel<<<blocks, threads, 0, stream>>>(x, t, W_s1, b_s1, W3, b3, Ws2,
                                                   out, M, T);
}

// Round 11
// 187.456 us; speedup vs baseline: 1.3696x; 1.3542x over previous
//
#include <hip/hip_runtime.h>

#define H1 64
#define GAMMA 0.1f

// ---- DS-free cross-lane reductions (all VALU pipe) ----
// DPP xor-pattern folds within a 16-lane row. Masks {1,2,7,15} span F_2^4,
// so after all four every lane holds the full 16-lane row sum.
#define DPP_QUAD_XOR1  0xB1   // quad_perm [1,0,3,2]  -> partner lane^1
#define DPP_QUAD_XOR2  0x4E   // quad_perm [2,3,0,1]  -> partner lane^2
#define DPP_HALF_MIRR  0x141  // row_half_mirror      -> partner lane^7
#define DPP_ROW_MIRR   0x140  // row_mirror           -> partner lane^15

// dpp ctrl must be an integer-constant-expression AT THE CALL SITE
// (round-4 compile fail: a function parameter is not an ICE) -> template.
template <int CTRL>
static __device__ __forceinline__ float dpp_add(float v) {
    int p = __builtin_amdgcn_update_dpp(0, __float_as_int(v), CTRL, 0xF, 0xF, true);
    return v + __int_as_float(p);
}
static __device__ __forceinline__ float red_row16(float v) {
    v = dpp_add<DPP_QUAD_XOR1>(v);
    v = dpp_add<DPP_QUAD_XOR2>(v);
    v = dpp_add<DPP_HALF_MIRR>(v);
    v = dpp_add<DPP_ROW_MIRR>(v);
    return v;
}

// fold16: v += v[lane^16]; fold32: v += v[lane^32]. gfx950 permlane*_swap
// returns both halves; with A=B=v, r.x + r.y is the butterfly sum everywhere.
static __device__ __forceinline__ float fold16(float v) {
#if __has_builtin(__builtin_amdgcn_permlane16_swap)
    typedef unsigned u32x2 __attribute__((ext_vector_type(2)));
    u32x2 r = __builtin_amdgcn_permlane16_swap(__float_as_uint(v),
                                               __float_as_uint(v), false, false);
    return __uint_as_float(r.x) + __uint_as_float(r.y);
#else
    return v + __shfl_xor(v, 16);
#endif
}
static __device__ __forceinline__ float fold32(float v) {
#if __has_builtin(__builtin_amdgcn_permlane32_swap)
    typedef unsigned u32x2 __attribute__((ext_vector_type(2)));
    u32x2 r = __builtin_amdgcn_permlane32_swap(__float_as_uint(v),
                                               __float_as_uint(v), false, false);
    return __uint_as_float(r.x) + __uint_as_float(r.y);
#else
    return v + __shfl_xor(v, 32);
#endif
}
static __device__ __forceinline__ float fold64(float v) { return fold32(fold16(v)); }

// One wave per row m; lane h owns channel h's scalar SIR ODE (beta constant).
// R is never integrated: S+I+R is conserved per channel, so
// dot(R, W3_k) = cst_k - dot(S, W3_k) - dot(I, W3_k).
// NO lambdas, NO arrays: everything is a named scalar so state stays in VGPRs
// (round-3 post-mortem: lambda-captured state + arrays went to LDS/scratch).
__global__ __launch_bounds__(256) void sir_ode_kernel(
    const float* __restrict__ x,
    const float* __restrict__ t,
    const float* __restrict__ W_s1,
    const float* __restrict__ b_s1,
    const float* __restrict__ W3,
    const float* __restrict__ b3,
    const float* __restrict__ Ws2,
    float* __restrict__ out,
    int M, int T)
{
    const int gtid = blockIdx.x * blockDim.x + threadIdx.x;
    const int m = gtid >> 6;
    const int lane = threadIdx.x & 63;
    if (m >= M) return;

    const int C = H1 + 3;
    const int g = (lane >> 4) & 3;   // this 16-lane row owns W3 row k=g

    const float w30 = W3[0 * H1 + lane];
    const float w31 = W3[1 * H1 + lane];
    const float w32 = W3[2 * H1 + lane];
    const float w33 = W3[3 * H1 + lane];
    const float b3g  = b3[g];
    const float ws2g = Ws2[g];

    const float S0  = x[(size_t)m * C + 0];
    const float I0  = x[(size_t)m * C + 1];
    const float bgv = x[(size_t)m * C + 3 + lane];
    const float w1  = W_s1[lane];
    const float bb  = b_s1[lane];

    float S = fmaxf(fmaf(S0, w1, bb), 0.0f);
    float I = fmaxf(fmaf(I0, w1, bb), 0.0f);
    const float beta = 0.5f / (1.0f + __expf(-bgv));

    // conserved-total constant for this lane's k-group:
    // cst = sum_h W3[g,h] * (S0c[h] + I0c[h])
    float cst;
    {
        const float tot = S + I;
        float c0 = fold64(tot * w30);
        float c1 = fold64(tot * w31);
        float c2 = fold64(tot * w32);
        float c3 = fold64(tot * w33);
        float cA = (g & 1) ? c1 : c0;
        float cB = (g & 1) ? c3 : c2;
        cst = red_row16((g & 2) ? cB : cA);
    }

    const size_t TM = (size_t)T * (size_t)M;
    float* op = out + (size_t)m;          // advances by M each step
    float t_cur = t[0];

    for (int ti = 0; ti < T; ++ti) {
        // uniform scalar prefetch of next time point (hidden under the head)
        const bool last = (ti + 1 >= T);
        const float t_next = last ? t_cur : t[ti + 1];
        const float dt = t_next - t_cur;          // 0 on the last step
        t_cur = t_next;

        // ---- head: 8 per-lane partials (S,I) x (4 W3 rows); R via cst
        float aS0 = fold64(S * w30);
        float aS1 = fold64(S * w31);
        float aS2 = fold64(S * w32);
        float aS3 = fold64(S * w33);
        float aI0 = fold64(I * w30);
        float aI1 = fold64(I * w31);
        float aI2 = fold64(I * w32);
        float aI3 = fold64(I * w33);

        // specialize per 16-lane row (k = g), finish the 64-wide dots
        float qsA = (g & 1) ? aS1 : aS0;
        float qsB = (g & 1) ? aS3 : aS2;
        float qs  = red_row16((g & 2) ? qsB : qsA);
        float qiA = (g & 1) ? aI1 : aI0;
        float qiB = (g & 1) ? aI3 : aI2;
        float qi  = red_row16((g & 2) ? qiB : qiA);
        float qr  = cst - qs - qi;

        // per-k nonlinearity, then sum the 4 k-groups (bs2 cancels in softmax)
        float h0 = fold64(fmaxf(qs + b3g, 0.0f) * ws2g);
        float h1 = fold64(fmaxf(qi + b3g, 0.0f) * ws2g);
        float h2 = fold64(fmaxf(qr + b3g, 0.0f) * ws2g);

        // softmax over the 3 states
        float mx = fmaxf(fmaxf(h0, h1), h2);
        float e0 = __expf(h0 - mx);
        float e1 = __expf(h1 - mx);
        float e2 = __expf(h2 - mx);
        float rs = 1.0f / (e0 + e1 + e2);

        if (lane < 3) {
            float v = (lane == 0) ? e0 * rs : ((lane == 1) ? e1 * rs : e2 * rs);
            op[(size_t)lane * TM] = v;
        }
        op += M;

        // ---- RK4 advance of (S,I); dt==0 on the last step is an exact no-op.
        // Independent of the head tree above -> free ILP for the scheduler.
        const float hdt = 0.5f * dt;
        float inf1 = beta * S * I;
        float I2 = fmaf(hdt, fmaf(-GAMMA, I, inf1), I);
        float S2 = fmaf(-hdt, inf1, S);
        float inf2 = beta * S2 * I2;
        float S3 = fmaf(-hdt, inf2, S);
        float I3 = fmaf(hdt, fmaf(-GAMMA, I2, inf2), I);
        float inf3 = beta * S3 * I3;
        float S4 = fmaf(-dt, inf3, S);
        float I4 = fmaf(dt, fmaf(-GAMMA, I3, inf3), I);
        float inf4 = beta * S4 * I4;
        float sumInf = fmaf(2.0f, inf2 + inf3, inf1) + inf4;
        float A      = fmaf(2.0f, I2 + I3, I) + I4;
        float w = dt * (1.0f / 6.0f);
        S = fmaf(-w, sumInf, S);
        I = fmaf(w, fmaf(-GAMMA, A, sumInf), I);
    }
}

extern "C" void kernel_launch(void* const* d_in, const int* in_sizes, int n_in,
                              void* d_out, int out_size, void* d_ws, size_t ws_size,
                              hipStream_t stream) {
    const float* x    = (const float*)d_in[0];
    const float* t    = (const float*)d_in[1];
    const float* W_s1 = (const float*)d_in[2];
    const float* b_s1 = (const float*)d_in[3];
    const float* W3   = (const float*)d_in[4];
    const float* b3   = (const float*)d_in[5];
    const float* Ws2  = (const float*)d_in[6];
    // d_in[7] = bs2: cancels in the softmax, unused.
    float* out = (float*)d_out;

    const int M = in_sizes[0] / (H1 + 3);   // 4000
    const int T = in_sizes[1];              // 100

    const int threads = 256;                 // 4 waves/block
    const int blocks = (M * 64 + threads - 1) / threads;
    sir_ode_kernel<<<blocks, threads, 0, stream>>>(x, t, W_s1, b_s1, W3, b3, Ws2,
                                                   out, M, T);
}